// Round 1
// baseline (1344.226 us; speedup 1.0000x reference)
//
#include <hip/hip_runtime.h>
#include <hip/hip_bf16.h>
#include <cstddef>

// Problem constants: B=8, C=128, H=W=64, S=4 (16x16=256 blocks), 3 branches.

__device__ __forceinline__ float ins_pixel(int i, const float* __restrict__ F1,
                                           const float* __restrict__ F2,
                                           const float* __restrict__ F3,
                                           int b, int c, int y, int x) {
  if (i == 1) {
    return F2[(((size_t)b * 128 + c) * 64 + y) * 64 + x];
  } else if (i == 2) {
    // 2x2 mean pool of F3 (8,128,128,128)
    const float* p = F3 + (((size_t)b * 128 + c) * 128 + 2 * y) * 128 + 2 * x;
    return 0.25f * (p[0] + p[1] + p[128] + p[129]);
  } else {
    // bilinear 2x upsample of F1 (8,128,32,32), half-pixel, edge clamp
    int ky = y >> 1, kx = x >> 1;
    int y0, y1, x0, x1;
    float wy0, wx0;
    if (y & 1) { y0 = ky; y1 = (ky + 1 < 32) ? ky + 1 : 31; wy0 = 0.75f; }
    else       { y0 = (ky - 1 > 0) ? ky - 1 : 0; y1 = ky;   wy0 = 0.25f; }
    if (x & 1) { x0 = kx; x1 = (kx + 1 < 32) ? kx + 1 : 31; wx0 = 0.75f; }
    else       { x0 = (kx - 1 > 0) ? kx - 1 : 0; x1 = kx;   wx0 = 0.25f; }
    const float* p = F1 + ((size_t)b * 128 + c) * 1024;
    float top = wx0 * p[y0 * 32 + x0] + (1.f - wx0) * p[y0 * 32 + x1];
    float bot = wx0 * p[y1 * 32 + x0] + (1.f - wx0) * p[y1 * 32 + x1];
    return wy0 * top + (1.f - wy0) * bot;
  }
}

// conv_w (3,co,ci,3,3) -> WT [i][ci][k][co]
__global__ void k_transw(const float* __restrict__ conv_w, float* __restrict__ wT) {
  int idx = blockIdx.x * 256 + threadIdx.x;
  if (idx >= 3 * 128 * 128 * 9) return;
  int co = idx & 127;
  int k = (idx >> 7) % 9;
  int ci = (idx / 1152) & 127;
  int i = idx / 147456;
  wT[idx] = conv_w[(((size_t)(i * 128 + co)) * 128 + ci) * 9 + k];
}

// combT[(d*128+c)*128 + o] = sum_m out_w[o,m] * c3d_w[m,c,d]
__global__ void k_comb(const float* __restrict__ out_w, const float* __restrict__ c3d_w,
                       float* __restrict__ combT) {
  int idx = blockIdx.x * 256 + threadIdx.x;  // j*128 + o, total 49152
  int o = idx & 127, j = idx >> 7;
  int c = j & 127, d = j >> 7;
  float s = 0.f;
  for (int m = 0; m < 128; m++)
    s += out_w[o * 128 + m] * c3d_w[(m * 128 + c) * 3 + d];
  combT[idx] = s;
}

__global__ void k_fb(const float* __restrict__ out_w, const float* __restrict__ c3d_b,
                     const float* __restrict__ out_b, float* __restrict__ fb) {
  int o = threadIdx.x;
  float s = out_b[o];
  for (int m = 0; m < 128; m++) s += out_w[o * 128 + m] * c3d_b[m];
  fb[o] = s;
}

// block-mean of ins[i]: xavg[((i*8+b)*256+n)*128+c], block = (i,b,c,by), thread=(row,x)
__global__ void k_xavg(const float* __restrict__ F1, const float* __restrict__ F2,
                       const float* __restrict__ F3, float* __restrict__ xavg) {
  int bid = blockIdx.x;
  int by = bid & 15;
  int c = (bid >> 4) & 127;
  int b = (bid >> 11) & 7;
  int i = bid >> 14;
  int r = threadIdx.x >> 6;
  int x = threadIdx.x & 63;
  float v = ins_pixel(i, F1, F2, F3, b, c, by * 4 + r, x);
  __shared__ float sm[256];
  sm[threadIdx.x] = v;
  __syncthreads();
  if (threadIdx.x < 16) {
    float s = 0.f;
    for (int rr = 0; rr < 4; rr++)
      for (int dx = 0; dx < 4; dx++)
        s += sm[rr * 64 + threadIdx.x * 4 + dx];
    int n = by * 16 + threadIdx.x;
    xavg[(((size_t)i * 8 + b) * 256 + n) * 128 + c] = s * (1.f / 16.f);
  }
}

// Q,K,Vb projections. block = (i*8+b)*256+n, 128 threads (out channel)
__global__ void k_proj(const float* __restrict__ xavg,
                       const float* __restrict__ qw, const float* __restrict__ qb,
                       const float* __restrict__ kw, const float* __restrict__ kb,
                       const float* __restrict__ vw, const float* __restrict__ vb,
                       float* __restrict__ Q, float* __restrict__ Km, float* __restrict__ Vb) {
  int bid = blockIdx.x;
  int i = bid >> 11;
  int c = threadIdx.x;
  __shared__ float xr[128];
  xr[c] = xavg[(size_t)bid * 128 + c];
  __syncthreads();
  const float* qwr = qw + ((size_t)i * 128 + c) * 128;
  const float* kwr = kw + ((size_t)i * 128 + c) * 128;
  const float* vwr = vw + ((size_t)i * 128 + c) * 128;
  float sq = 0.f, sk = 0.f, sv = 0.f;
  #pragma unroll 4
  for (int k = 0; k < 128; k++) {
    float xv = xr[k];
    sq += xv * qwr[k];
    sk += xv * kwr[k];
    sv += xv * vwr[k];
  }
  Q[(size_t)bid * 128 + c] = sq + qb[i * 128 + c];
  Km[(size_t)bid * 128 + c] = sk + kb[i * 128 + c];
  Vb[(size_t)bid * 128 + c] = 16.f * (sv + vb[i * 128 + c]);
}

// attention row: block = (i*8+b)*256+n, 256 threads (m / key index)
__global__ void k_attn(const float* __restrict__ Q, const float* __restrict__ Km,
                       const float* __restrict__ Vb, float* __restrict__ OB) {
  int bid = blockIdx.x;
  int ib = bid >> 8;
  int t = threadIdx.x;
  __shared__ float qr[128];
  __shared__ float av[256];
  __shared__ float red[256];
  if (t < 128) qr[t] = Q[(size_t)bid * 128 + t];
  __syncthreads();
  const float* kr = Km + ((size_t)ib * 256 + t) * 128;
  float s = 0.f;
  #pragma unroll 4
  for (int k = 0; k < 128; k++) s += qr[k] * kr[k];
  s *= 0.08838834764831845f;  // 1/sqrt(128)
  red[t] = s;
  __syncthreads();
  for (int off = 128; off >= 1; off >>= 1) {
    if (t < off) red[t] = fmaxf(red[t], red[t + off]);
    __syncthreads();
  }
  float mx = red[0];
  __syncthreads();
  float e = expf(s - mx);
  av[t] = e;
  red[t] = e;
  __syncthreads();
  for (int off = 128; off >= 1; off >>= 1) {
    if (t < off) red[t] += red[t + off];
    __syncthreads();
  }
  float inv = 1.f / red[0];
  __syncthreads();
  int c = t & 127, half = t >> 7;
  const float* vbase = Vb + (size_t)ib * 256 * 128;
  float acc = 0.f;
  for (int m = half * 128; m < half * 128 + 128; m++)
    acc += av[m] * vbase[m * 128 + c];
  red[t] = acc;
  __syncthreads();
  if (t < 128)
    OB[(size_t)bid * 128 + t] = (red[t] + red[t + 128]) * inv;
}

// direct conv3x3 + attention add -> cat. block=(y,b,i), thread = 4co x 8x
__global__ __launch_bounds__(256) void k_conv(
    const float* __restrict__ F1, const float* __restrict__ F2, const float* __restrict__ F3,
    const float* __restrict__ WT, const float* __restrict__ conv_b,
    const float* __restrict__ OB, float* __restrict__ cat) {
  int y = blockIdx.x, b = blockIdx.y, i = blockIdx.z;
  int t = threadIdx.x;
  int cog = t >> 3, xg = t & 7;
  int o0 = cog * 4, x0 = xg * 8;
  __shared__ float sin_[3][68];   // row stride 272B (16B aligned), col j = x+1
  __shared__ float sw[1152];      // [k][co]
  float acc[4][8];
  #pragma unroll
  for (int a = 0; a < 4; a++)
    #pragma unroll
    for (int jj = 0; jj < 8; jj++) acc[a][jj] = 0.f;
  const float* wtb = WT + (size_t)i * 128 * 1152;
  for (int ci = 0; ci < 128; ci++) {
    if (t < 198) {
      int r = t / 66, j = t - r * 66;
      int yy = y - 1 + r, xx = j - 1;
      float v = 0.f;
      if (yy >= 0 && yy < 64 && xx >= 0 && xx < 64)
        v = ins_pixel(i, F1, F2, F3, b, ci, yy, xx);
      sin_[r][j] = v;
    }
    const float* wrow = wtb + (size_t)ci * 1152;
    #pragma unroll
    for (int l = 0; l < 5; l++) {
      int idx = t + l * 256;
      if (idx < 1152) sw[idx] = wrow[idx];
    }
    __syncthreads();
    float wk[9][4];
    #pragma unroll
    for (int k = 0; k < 9; k++) {
      float4 wv = *(const float4*)&sw[k * 128 + o0];
      wk[k][0] = wv.x; wk[k][1] = wv.y; wk[k][2] = wv.z; wk[k][3] = wv.w;
    }
    float v[3][12];
    #pragma unroll
    for (int r = 0; r < 3; r++) {
      float4 a = *(const float4*)&sin_[r][x0];
      float4 bq = *(const float4*)&sin_[r][x0 + 4];
      float4 cq = *(const float4*)&sin_[r][x0 + 8];
      v[r][0] = a.x;  v[r][1] = a.y;  v[r][2] = a.z;  v[r][3] = a.w;
      v[r][4] = bq.x; v[r][5] = bq.y; v[r][6] = bq.z; v[r][7] = bq.w;
      v[r][8] = cq.x; v[r][9] = cq.y; v[r][10] = cq.z; v[r][11] = cq.w;
    }
    #pragma unroll
    for (int oo = 0; oo < 4; oo++) {
      #pragma unroll
      for (int jj = 0; jj < 8; jj++) {
        float s = acc[oo][jj];
        s += wk[0][oo] * v[0][jj] + wk[1][oo] * v[0][jj + 1] + wk[2][oo] * v[0][jj + 2];
        s += wk[3][oo] * v[1][jj] + wk[4][oo] * v[1][jj + 1] + wk[5][oo] * v[1][jj + 2];
        s += wk[6][oo] * v[2][jj] + wk[7][oo] * v[2][jj + 1] + wk[8][oo] * v[2][jj + 2];
        acc[oo][jj] = s;
      }
    }
    __syncthreads();
  }
  int n_row = (y >> 2) * 16;
  const float* obb = OB + (((size_t)i * 8 + b) * 256 + n_row) * 128;
  #pragma unroll
  for (int oo = 0; oo < 4; oo++) {
    int co = o0 + oo;
    float bias = conv_b[i * 128 + co];
    float att0 = obb[(x0 >> 2) * 128 + co];
    float att1 = obb[((x0 >> 2) + 1) * 128 + co];
    float* outp = cat + ((((size_t)b * 384 + i * 128 + co) * 64 + y) * 64 + x0);
    #pragma unroll
    for (int jj = 0; jj < 8; jj++)
      outp[jj] = acc[oo][jj] + bias + (jj < 4 ? att0 : att1);
  }
}

// SE mean over HW: block per (b*384+j)
__global__ void k_semean(const float* __restrict__ cat, float* __restrict__ y) {
  int bj = blockIdx.x;
  int t = threadIdx.x;
  const float4* p = (const float4*)(cat + (size_t)bj * 4096);
  float s = 0.f;
  for (int k = t; k < 1024; k += 256) {
    float4 v = p[k];
    s += v.x + v.y + v.z + v.w;
  }
  __shared__ float red[256];
  red[t] = s;
  __syncthreads();
  for (int off = 128; off >= 1; off >>= 1) {
    if (t < off) red[t] += red[t + off];
    __syncthreads();
  }
  if (t == 0) y[bj] = red[0] * (1.f / 4096.f);
}

__global__ void k_semlp(const float* __restrict__ y,
                        const float* __restrict__ ca1_w, const float* __restrict__ ca1_b,
                        const float* __restrict__ ca2_w, const float* __restrict__ ca2_b,
                        float* __restrict__ yse) {
  int b = blockIdx.x;
  int t = threadIdx.x;  // 384 threads
  __shared__ float ysh[384];
  __shared__ float z1[24];
  ysh[t] = y[b * 384 + t];
  __syncthreads();
  if (t < 24) {
    float s = ca1_b[t];
    for (int k = 0; k < 384; k++) s += ca1_w[t * 384 + k] * ysh[k];
    z1[t] = fmaxf(s, 0.f);
  }
  __syncthreads();
  float s = ca2_b[t];
  for (int k = 0; k < 24; k++) s += ca2_w[t * 24 + k] * z1[k];
  yse[b * 384 + t] = 1.f / (1.f + expf(-s));
}

// fused SE-scale + conv3d-depth + 1x1: out[b,o,p] = sum_j combT[j,o]*yse[b,j]*cat[b,j,p] + fb[o]
// block = (y2 in 0..31, b), thread = 8o x 8p (2 rows of 64)
__global__ __launch_bounds__(256) void k_final(
    const float* __restrict__ cat, const float* __restrict__ combT,
    const float* __restrict__ yse, const float* __restrict__ fb, float* __restrict__ out) {
  int y2 = blockIdx.x;
  int b = blockIdx.y;
  int t = threadIdx.x;
  int og = t >> 4, o0 = og * 8;
  int pg = t & 15, p0 = pg * 8;
  __shared__ float ys[384];
  __shared__ float srow[128];
  __shared__ float scomb[128];
  for (int j = t; j < 384; j += 256) ys[j] = yse[b * 384 + j];
  float acc[8][8];
  #pragma unroll
  for (int a = 0; a < 8; a++)
    #pragma unroll
    for (int p = 0; p < 8; p++) acc[a][p] = 0.f;
  __syncthreads();
  for (int j = 0; j < 384; j++) {
    if (t < 128) {
      srow[t] = cat[(((size_t)b * 384 + j) * 64 + y2 * 2 + (t >> 6)) * 64 + (t & 63)];
    } else {
      scomb[t - 128] = combT[j * 128 + (t - 128)];
    }
    __syncthreads();
    float yj = ys[j];
    float4 cwa = *(const float4*)&scomb[o0];
    float4 cwb = *(const float4*)&scomb[o0 + 4];
    float4 rva = *(const float4*)&srow[p0];
    float4 rvb = *(const float4*)&srow[p0 + 4];
    float cw[8] = {cwa.x * yj, cwa.y * yj, cwa.z * yj, cwa.w * yj,
                   cwb.x * yj, cwb.y * yj, cwb.z * yj, cwb.w * yj};
    float rv[8] = {rva.x, rva.y, rva.z, rva.w, rvb.x, rvb.y, rvb.z, rvb.w};
    #pragma unroll
    for (int oo = 0; oo < 8; oo++)
      #pragma unroll
      for (int pp = 0; pp < 8; pp++)
        acc[oo][pp] += cw[oo] * rv[pp];
    __syncthreads();
  }
  #pragma unroll
  for (int oo = 0; oo < 8; oo++) {
    int o = o0 + oo;
    float bias = fb[o];
    #pragma unroll
    for (int pp = 0; pp < 8; pp++)
      out[((size_t)b * 128 + o) * 4096 + y2 * 128 + p0 + pp] = acc[oo][pp] + bias;
  }
}

extern "C" void kernel_launch(void* const* d_in, const int* in_sizes, int n_in,
                              void* d_out, int out_size, void* d_ws, size_t ws_size,
                              hipStream_t stream) {
  const float* F1 = (const float*)d_in[0];
  const float* F2 = (const float*)d_in[1];
  const float* F3 = (const float*)d_in[2];
  const float* conv_w = (const float*)d_in[3];
  const float* conv_b = (const float*)d_in[4];
  const float* qw = (const float*)d_in[5];
  const float* qb = (const float*)d_in[6];
  const float* kw = (const float*)d_in[7];
  const float* kb = (const float*)d_in[8];
  const float* vw = (const float*)d_in[9];
  const float* vb = (const float*)d_in[10];
  const float* ca1_w = (const float*)d_in[11];
  const float* ca1_b = (const float*)d_in[12];
  const float* ca2_w = (const float*)d_in[13];
  const float* ca2_b = (const float*)d_in[14];
  const float* c3d_w = (const float*)d_in[15];
  const float* c3d_b = (const float*)d_in[16];
  const float* out_w = (const float*)d_in[17];
  const float* out_b = (const float*)d_in[18];
  float* out = (float*)d_out;

  float* ws = (float*)d_ws;
  // ws layout (floats), total ~17.0M floats = 68 MB
  float* CAT   = ws;                    // 8*384*4096 = 12,582,912
  float* WT    = CAT + 12582912;        // 442,368
  float* XAVG  = WT + 442368;           // 786,432
  float* Qb    = XAVG + 786432;         // 786,432
  float* Kb    = Qb + 786432;           // 786,432
  float* VBb   = Kb + 786432;           // 786,432
  float* OBb   = VBb + 786432;          // 786,432
  float* Y     = OBb + 786432;          // 3,072
  float* YSE   = Y + 3072;              // 3,072
  float* COMBT = YSE + 3072;            // 49,152
  float* FB    = COMBT + 49152;         // 128

  k_transw<<<1728, 256, 0, stream>>>(conv_w, WT);
  k_comb<<<192, 256, 0, stream>>>(out_w, c3d_w, COMBT);
  k_fb<<<1, 128, 0, stream>>>(out_w, c3d_b, out_b, FB);
  k_xavg<<<49152, 256, 0, stream>>>(F1, F2, F3, XAVG);
  k_proj<<<6144, 128, 0, stream>>>(XAVG, qw, qb, kw, kb, vw, vb, Qb, Kb, VBb);
  k_attn<<<6144, 256, 0, stream>>>(Qb, Kb, VBb, OBb);
  k_conv<<<dim3(64, 8, 3), 256, 0, stream>>>(F1, F2, F3, WT, conv_b, OBb, CAT);
  k_semean<<<3072, 256, 0, stream>>>(CAT, Y);
  k_semlp<<<8, 384, 0, stream>>>(Y, ca1_w, ca1_b, ca2_w, ca2_b, YSE);
  k_final<<<dim3(32, 8), 256, 0, stream>>>(CAT, COMBT, YSE, FB, out);
}

// Round 2
// 301.956 us; speedup vs baseline: 4.4517x; 4.4517x over previous
//
#include <hip/hip_runtime.h>
#include <hip/hip_bf16.h>
#include <cstddef>

// B=8, C=128, H=W=64, S=4 (16x16=256 blocks), 3 branches.

typedef __bf16 bf16x8 __attribute__((ext_vector_type(8)));
typedef float f32x4 __attribute__((ext_vector_type(4)));

__device__ __forceinline__ unsigned short f2bf(float f) {
  unsigned int u = __float_as_uint(f);
  return (unsigned short)((u + 0x7fffu + ((u >> 16) & 1u)) >> 16);
}
__device__ __forceinline__ float bf2f(unsigned short h) {
  return __uint_as_float(((unsigned int)h) << 16);
}

__device__ __forceinline__ float ins_pixel(int i, const float* __restrict__ F1,
                                           const float* __restrict__ F2,
                                           const float* __restrict__ F3,
                                           int b, int c, int y, int x) {
  if (i == 1) {
    return F2[(((size_t)b * 128 + c) * 64 + y) * 64 + x];
  } else if (i == 2) {
    const float* p = F3 + (((size_t)b * 128 + c) * 128 + 2 * y) * 128 + 2 * x;
    return 0.25f * (p[0] + p[1] + p[128] + p[129]);
  } else {
    int ky = y >> 1, kx = x >> 1;
    int y0, y1, x0, x1;
    float wy0, wx0;
    if (y & 1) { y0 = ky; y1 = (ky + 1 < 32) ? ky + 1 : 31; wy0 = 0.75f; }
    else       { y0 = (ky - 1 > 0) ? ky - 1 : 0; y1 = ky;   wy0 = 0.25f; }
    if (x & 1) { x0 = kx; x1 = (kx + 1 < 32) ? kx + 1 : 31; wx0 = 0.75f; }
    else       { x0 = (kx - 1 > 0) ? kx - 1 : 0; x1 = kx;   wx0 = 0.25f; }
    const float* p = F1 + ((size_t)b * 128 + c) * 1024;
    float top = wx0 * p[y0 * 32 + x0] + (1.f - wx0) * p[y0 * 32 + x1];
    float bot = wx0 * p[y1 * 32 + x0] + (1.f - wx0) * p[y1 * 32 + x1];
    return wy0 * top + (1.f - wy0) * bot;
  }
}

// conv_w (3,co,ci,3,3) fp32 -> WG bf16 [i][tap][co][ci]
__global__ void k_wprep(const float* __restrict__ conv_w, unsigned short* __restrict__ WG) {
  int idx = blockIdx.x * 256 + threadIdx.x;
  if (idx >= 3 * 9 * 128 * 128) return;
  int ci = idx & 127;
  int co = (idx >> 7) & 127;
  int tap = (idx >> 14) % 9;
  int i = idx / (9 * 128 * 128);
  WG[idx] = f2bf(conv_w[(((size_t)(i * 128 + co)) * 128 + ci) * 9 + tap]);
}

// comb2[o][j] = sum_m out_w[o,m]*c3d_w[m,c,d], j = d*128+c
__global__ void k_comb2(const float* __restrict__ out_w, const float* __restrict__ c3d_w,
                        float* __restrict__ comb2) {
  int idx = blockIdx.x * 256 + threadIdx.x;  // o*384 + j, 49152 total
  int j = idx % 384, o = idx / 384;
  int c = j & 127, d = j >> 7;
  float s = 0.f;
  for (int m = 0; m < 128; m++)
    s += out_w[o * 128 + m] * c3d_w[(m * 128 + c) * 3 + d];
  comb2[idx] = s;
}

__global__ void k_fb(const float* __restrict__ out_w, const float* __restrict__ c3d_b,
                     const float* __restrict__ out_b, float* __restrict__ fb) {
  int o = threadIdx.x;
  float s = out_b[o];
  for (int m = 0; m < 128; m++) s += out_w[o * 128 + m] * c3d_b[m];
  fb[o] = s;
}

// qw/kw/vw (3,C,C) -> transposed fp32 [i][k][c]
__global__ void k_qkvT(const float* __restrict__ qw, const float* __restrict__ kw,
                       const float* __restrict__ vw, float* __restrict__ qwT,
                       float* __restrict__ kwT, float* __restrict__ vwT) {
  int idx = blockIdx.x * 256 + threadIdx.x;
  if (idx >= 3 * 128 * 128) return;
  int c = idx & 127, k = (idx >> 7) & 127, i = idx >> 14;
  int src = (i * 128 + c) * 128 + k;
  qwT[idx] = qw[src];
  kwT[idx] = kw[src];
  vwT[idx] = vw[src];
}

// INS bf16 NHWC [i][b][y][x][ci]  +  XAVG f32 [(i*8+b)*256+n][c]
__global__ __launch_bounds__(256) void k_prep(
    const float* __restrict__ F1, const float* __restrict__ F2, const float* __restrict__ F3,
    unsigned short* __restrict__ INS, float* __restrict__ XAVG) {
  int yg = blockIdx.x, b = blockIdx.y, i = blockIdx.z;
  int ib = i * 8 + b;
  int t = threadIdx.x;
  __shared__ unsigned short L[128 * 66];
  int x = t & 63, cg = t >> 6;
  int c2 = t & 127, xh = t >> 7;
  float acc8[8];
#pragma unroll
  for (int z = 0; z < 8; z++) acc8[z] = 0.f;
  for (int ry = 0; ry < 4; ++ry) {
    int y = yg * 4 + ry;
    for (int k = 0; k < 32; ++k) {
      int c = cg * 32 + k;
      L[c * 66 + x] = f2bf(ins_pixel(i, F1, F2, F3, b, c, y, x));
    }
    __syncthreads();
    // xavg accumulate (reads bf16-rounded values, consistent with conv input)
    for (int xx = xh * 32; xx < xh * 32 + 32; ++xx)
      acc8[(xx >> 2) & 7] += bf2f(L[c2 * 66 + xx]);
    // coalesced NHWC write
    for (int q = 0; q < 4; ++q) {
      int id = t + 256 * q;           // 1024 chunks of 16B
      int xx = id >> 4, cseg = id & 15;
      alignas(16) unsigned short tmp[8];
#pragma unroll
      for (int cc = 0; cc < 8; ++cc) tmp[cc] = L[(cseg * 8 + cc) * 66 + xx];
      *(uint4*)(INS + (((size_t)ib * 64 + y) * 64 + xx) * 128 + cseg * 8) = *(uint4*)tmp;
    }
    __syncthreads();
  }
#pragma unroll
  for (int bb = 0; bb < 8; ++bb) {
    int n = yg * 16 + xh * 8 + bb;
    XAVG[((size_t)(ib * 256 + n)) * 128 + c2] = acc8[bb] * (1.f / 16.f);
  }
}

// Q,K,Vb projections. block=(nc,b,i): 32 n rows each.
__global__ __launch_bounds__(256) void k_proj(
    const float* __restrict__ xavg, const float* __restrict__ qwT, const float* __restrict__ qb,
    const float* __restrict__ kwT, const float* __restrict__ kb,
    const float* __restrict__ vwT, const float* __restrict__ vb,
    float* __restrict__ Q, float* __restrict__ Km, float* __restrict__ Vb) {
  int nc = blockIdx.x, b = blockIdx.y, i = blockIdx.z;
  int ib = i * 8 + b;
  int t = threadIdx.x;
  __shared__ float xs[32 * 128];
  for (int q = 0; q < 4; ++q) {
    int id = t + 256 * q;              // 1024 chunks of 16B
    int n = id >> 5, seg = id & 31;
    float4 v = *(const float4*)(xavg + ((size_t)(ib * 256 + nc * 32 + n)) * 128 + seg * 4);
    *(float4*)(xs + n * 128 + seg * 4) = v;
  }
  __syncthreads();
  int c = t & 127, nh = t >> 7;
  float aq[16], ak[16], av[16];
#pragma unroll
  for (int z = 0; z < 16; z++) { aq[z] = 0.f; ak[z] = 0.f; av[z] = 0.f; }
  for (int k = 0; k < 128; ++k) {
    float wq = qwT[(i * 128 + k) * 128 + c];
    float wk = kwT[(i * 128 + k) * 128 + c];
    float wv = vwT[(i * 128 + k) * 128 + c];
#pragma unroll
    for (int nn = 0; nn < 16; ++nn) {
      float xv = xs[(nh * 16 + nn) * 128 + k];
      aq[nn] += xv * wq; ak[nn] += xv * wk; av[nn] += xv * wv;
    }
  }
  float bq = qb[i * 128 + c], bk = kb[i * 128 + c], bv = vb[i * 128 + c];
#pragma unroll
  for (int nn = 0; nn < 16; ++nn) {
    size_t row = ((size_t)(ib * 256 + nc * 32 + nh * 16 + nn)) * 128 + c;
    Q[row] = aq[nn] + bq;
    Km[row] = ak[nn] + bk;
    Vb[row] = 16.f * (av[nn] + bv);
  }
}

// attention: block=(nc,b,i): 16 q-rows; 2-pass softmax, K/V chunks in LDS
__global__ __launch_bounds__(256) void k_attn(
    const float* __restrict__ Q, const float* __restrict__ K, const float* __restrict__ V,
    float* __restrict__ OB) {
  int nc = blockIdx.x, b = blockIdx.y, i = blockIdx.z;
  int ib = i * 8 + b;
  int t = threadIdx.x;
  __shared__ float Qs[16 * 132];
  __shared__ float Ss[16 * 257];
  __shared__ float KVs[32 * 132];
  for (int q = 0; q < 2; ++q) {
    int id = t + 256 * q;             // 512 chunks
    int n = id >> 5, seg = id & 31;
    float4 v = *(const float4*)(Q + ((size_t)(ib * 256 + nc * 16 + n)) * 128 + seg * 4);
    *(float4*)(Qs + n * 132 + seg * 4) = v;
  }
  int n = t >> 4, ms = t & 15;
  const float SC = 0.08838834764831845f;
  // pass 1: scores
  for (int mc = 0; mc < 8; ++mc) {
    __syncthreads();
    for (int q = 0; q < 4; ++q) {
      int id = t + 256 * q;
      int m = id >> 5, seg = id & 31;
      float4 v = *(const float4*)(K + ((size_t)(ib * 256 + mc * 32 + m)) * 128 + seg * 4);
      *(float4*)(KVs + m * 132 + seg * 4) = v;
    }
    __syncthreads();
    float s0 = 0.f, s1 = 0.f;
    const float* qrow = Qs + n * 132;
    const float* k0p = KVs + (ms * 2) * 132;
    for (int kg = 0; kg < 32; ++kg) {
      float4 qv = *(const float4*)(qrow + kg * 4);
      float4 k0 = *(const float4*)(k0p + kg * 4);
      float4 k1 = *(const float4*)(k0p + 132 + kg * 4);
      s0 += qv.x * k0.x + qv.y * k0.y + qv.z * k0.z + qv.w * k0.w;
      s1 += qv.x * k1.x + qv.y * k1.y + qv.z * k1.z + qv.w * k1.w;
    }
    Ss[n * 257 + mc * 32 + ms * 2 + 0] = s0 * SC;
    Ss[n * 257 + mc * 32 + ms * 2 + 1] = s1 * SC;
  }
  __syncthreads();
  // softmax over 256 per row n (16 threads per row)
  {
    float vals[16];
    float mx = -1e30f;
#pragma unroll
    for (int j = 0; j < 16; ++j) { vals[j] = Ss[n * 257 + ms + 16 * j]; mx = fmaxf(mx, vals[j]); }
    for (int d = 1; d < 16; d <<= 1) mx = fmaxf(mx, __shfl_xor(mx, d));
    float sum = 0.f;
#pragma unroll
    for (int j = 0; j < 16; ++j) { vals[j] = __expf(vals[j] - mx); sum += vals[j]; }
    for (int d = 1; d < 16; d <<= 1) sum += __shfl_xor(sum, d);
    float inv = 1.f / sum;
#pragma unroll
    for (int j = 0; j < 16; ++j) Ss[n * 257 + ms + 16 * j] = vals[j] * inv;
  }
  // pass 2: PV
  int cs = ms;
  float acc[8];
#pragma unroll
  for (int z = 0; z < 8; z++) acc[z] = 0.f;
  for (int mc = 0; mc < 8; ++mc) {
    __syncthreads();
    for (int q = 0; q < 4; ++q) {
      int id = t + 256 * q;
      int m = id >> 5, seg = id & 31;
      float4 v = *(const float4*)(V + ((size_t)(ib * 256 + mc * 32 + m)) * 128 + seg * 4);
      *(float4*)(KVs + m * 132 + seg * 4) = v;
    }
    __syncthreads();
    for (int m = 0; m < 32; ++m) {
      float p = Ss[n * 257 + mc * 32 + m];
      const float* vrow = KVs + m * 132 + cs * 8;
      float4 v0 = *(const float4*)(vrow);
      float4 v1 = *(const float4*)(vrow + 4);
      acc[0] += p * v0.x; acc[1] += p * v0.y; acc[2] += p * v0.z; acc[3] += p * v0.w;
      acc[4] += p * v1.x; acc[5] += p * v1.y; acc[6] += p * v1.z; acc[7] += p * v1.w;
    }
  }
  float* orow = OB + ((size_t)(ib * 256 + nc * 16 + n)) * 128 + cs * 8;
  *(float4*)(orow) = make_float4(acc[0], acc[1], acc[2], acc[3]);
  *(float4*)(orow + 4) = make_float4(acc[4], acc[5], acc[6], acc[7]);
}

// conv3x3 via bf16 MFMA implicit GEMM + attention add -> catT bf16 [b][p][j]
// block=(ypair, b, i): 128co x 128px (2 rows). 4 waves, each 64co x 64px.
__global__ __launch_bounds__(256) void k_conv(
    const unsigned short* __restrict__ INS, const unsigned short* __restrict__ WG,
    const float* __restrict__ conv_b, const float* __restrict__ OB,
    unsigned short* __restrict__ catT) {
  int y0 = blockIdx.x * 2, b = blockIdx.y, i = blockIdx.z;
  int ib = i * 8 + b;
  int t = threadIdx.x;
  // LDS: Xs [4][66][40] = 10560 | Wb0 [128][40] = 5120 | Wb1 = 5120  (ushorts)
  __shared__ alignas(16) unsigned short smem[20800];
  unsigned short* Xs = smem;
  unsigned short* Wb0 = smem + 10560;
  unsigned short* Wb1 = smem + 15680;

  int w = t >> 6, l = t & 63;
  int wm = w >> 1, wr = w & 1;
  int lr = l & 15, lk = (l >> 4) * 8;

  f32x4 acc[4][4];
#pragma unroll
  for (int s = 0; s < 4; s++)
#pragma unroll
    for (int p = 0; p < 4; p++) acc[s][p] = 0.f;

  // stage X chunk cc (32 ci)
  auto stageX = [&](int cc) {
    for (int cI = t; cI < 1056; cI += 256) {
      int seg = cI & 3, rj = cI >> 2;
      int r = rj / 66, j = rj - r * 66;
      int yy = y0 - 1 + r, xx = j - 1;
      uint4 v = {0u, 0u, 0u, 0u};
      if (yy >= 0 && yy < 64 && xx >= 0 && xx < 64)
        v = *(const uint4*)(INS + (((size_t)ib * 64 + yy) * 64 + xx) * 128 + cc * 32 + seg * 8);
      *(uint4*)(&Xs[(r * 66 + j) * 40 + seg * 8]) = v;
    }
  };

  stageX(0);
  // stage W(0) direct
  {
    for (int q = 0; q < 2; ++q) {
      int id = t + 256 * q;
      int co = id >> 2, seg = id & 3;
      uint4 v = *(const uint4*)(WG + ((size_t)(i * 9 + 0) * 128 + co) * 128 + 0 * 32 + seg * 8);
      *(uint4*)(&Wb0[co * 40 + seg * 8]) = v;
    }
  }
  __syncthreads();

  for (int s = 0; s < 36; ++s) {
    int tap = s % 9, cc = s / 9;
    int dy = tap / 3, dx = tap - dy * 3;
    unsigned short* Wcur = (s & 1) ? Wb1 : Wb0;
    unsigned short* Wnxt = (s & 1) ? Wb0 : Wb1;
    uint4 wpf[2];
    if (s < 35) {
      int sN = s + 1, tapN = sN % 9, ccN = sN / 9;
#pragma unroll
      for (int q = 0; q < 2; ++q) {
        int id = t + 256 * q;
        int co = id >> 2, seg = id & 3;
        wpf[q] = *(const uint4*)(WG + ((size_t)(i * 9 + tapN) * 128 + co) * 128 + ccN * 32 + seg * 8);
      }
    }
    // compute: K=32 (one MFMA step), 4x4 fragments per wave
    {
      bf16x8 af[4], bf_[4];
#pragma unroll
      for (int sf = 0; sf < 4; ++sf)
        af[sf] = *(const bf16x8*)(&Wcur[(wm * 64 + sf * 16 + lr) * 40 + lk]);
      int r = wr + dy;
#pragma unroll
      for (int p = 0; p < 4; ++p) {
        int j = p * 16 + lr + dx;
        bf_[p] = *(const bf16x8*)(&Xs[(r * 66 + j) * 40 + lk]);
      }
#pragma unroll
      for (int sf = 0; sf < 4; ++sf)
#pragma unroll
        for (int p = 0; p < 4; ++p)
          acc[sf][p] = __builtin_amdgcn_mfma_f32_16x16x32_bf16(af[sf], bf_[p], acc[sf][p], 0, 0, 0);
    }
    if (tap == 8 && s < 35) {
      __syncthreads();     // all waves done reading Xs(cc)
      stageX(cc + 1);
    }
    if (s < 35) {
#pragma unroll
      for (int q = 0; q < 2; ++q) {
        int id = t + 256 * q;
        int co = id >> 2, seg = id & 3;
        *(uint4*)(&Wnxt[co * 40 + seg * 8]) = wpf[q];
      }
    }
    __syncthreads();
  }

  // epilogue: + bias + attention, bf16, LDS transpose, coalesced catT write
  unsigned short* Tt = smem;  // [128 ploc][136 co]
  float cb[4][4];
#pragma unroll
  for (int sf = 0; sf < 4; ++sf)
#pragma unroll
    for (int q = 0; q < 4; ++q)
      cb[sf][q] = conv_b[i * 128 + wm * 64 + sf * 16 + (l >> 4) * 4 + q];
#pragma unroll
  for (int sf = 0; sf < 4; ++sf) {
#pragma unroll
    for (int p = 0; p < 4; ++p) {
      int px = p * 16 + lr;
      int n = ((y0 + wr) >> 2) * 16 + (px >> 2);
      const float* ob = OB + ((size_t)(ib * 256 + n)) * 128;
      int cobase = wm * 64 + sf * 16 + (l >> 4) * 4;
      float v0 = acc[sf][p][0] + cb[sf][0] + ob[cobase + 0];
      float v1 = acc[sf][p][1] + cb[sf][1] + ob[cobase + 1];
      float v2 = acc[sf][p][2] + cb[sf][2] + ob[cobase + 2];
      float v3 = acc[sf][p][3] + cb[sf][3] + ob[cobase + 3];
      int ploc = wr * 64 + px;
      unsigned int pk0 = (unsigned int)f2bf(v0) | ((unsigned int)f2bf(v1) << 16);
      unsigned int pk1 = (unsigned int)f2bf(v2) | ((unsigned int)f2bf(v3) << 16);
      *(unsigned int*)(&Tt[ploc * 136 + cobase]) = pk0;
      *(unsigned int*)(&Tt[ploc * 136 + cobase + 2]) = pk1;
    }
  }
  __syncthreads();
  for (int c2 = t; c2 < 2048; c2 += 256) {
    int ploc = c2 >> 4, seg = c2 & 15;
    uint4 v = *(const uint4*)(&Tt[ploc * 136 + seg * 8]);
    int yy = y0 + (ploc >> 6), xx = ploc & 63;
    *(uint4*)(catT + (((size_t)b * 4096) + yy * 64 + xx) * 384 + i * 128 + seg * 8) = v;
  }
}

// SE mean stage 1: partial sums over 256 rows of p
__global__ void k_semean1(const unsigned short* __restrict__ catT, float* __restrict__ Ypart) {
  int pc = blockIdx.x, b = blockIdx.y;
  int j = threadIdx.x;  // 384
  const unsigned short* base = catT + ((size_t)b * 4096 + pc * 256) * 384 + j;
  float s = 0.f;
#pragma unroll 4
  for (int r = 0; r < 256; ++r) s += bf2f(base[(size_t)r * 384]);
  Ypart[(b * 16 + pc) * 384 + j] = s;
}

__global__ void k_semean2(const float* __restrict__ Ypart, float* __restrict__ Y) {
  int b = blockIdx.x;
  int j = threadIdx.x;
  float s = 0.f;
#pragma unroll
  for (int pc = 0; pc < 16; ++pc) s += Ypart[(b * 16 + pc) * 384 + j];
  Y[b * 384 + j] = s * (1.f / 4096.f);
}

__global__ void k_semlp(const float* __restrict__ y,
                        const float* __restrict__ ca1_w, const float* __restrict__ ca1_b,
                        const float* __restrict__ ca2_w, const float* __restrict__ ca2_b,
                        float* __restrict__ yse) {
  int b = blockIdx.x;
  int t = threadIdx.x;  // 384
  __shared__ float ysh[384];
  __shared__ float z1[24];
  ysh[t] = y[b * 384 + t];
  __syncthreads();
  if (t < 24) {
    float s = ca1_b[t];
    for (int k = 0; k < 384; k++) s += ca1_w[t * 384 + k] * ysh[k];
    z1[t] = fmaxf(s, 0.f);
  }
  __syncthreads();
  float s = ca2_b[t];
  for (int k = 0; k < 24; k++) s += ca2_w[t * 24 + k] * z1[k];
  yse[b * 384 + t] = 1.f / (1.f + expf(-s));
}

// A_bf[b][o][j] = bf16(comb2[o][j] * yse[b][j])
__global__ void k_sefold(const float* __restrict__ comb2, const float* __restrict__ yse,
                         unsigned short* __restrict__ Abf) {
  int idx = blockIdx.x * 256 + threadIdx.x;  // (b*128+o)*384 + j
  int j = idx % 384;
  int bo = idx / 384;
  int o = bo & 127, b = bo >> 7;
  Abf[idx] = f2bf(comb2[o * 384 + j] * yse[b * 384 + j]);
}

// final GEMM: out[b,o,p] = sum_j Abf[b,o,j] * catT[b,p,j] + fb[o]
// block=(pc,b): 128o x 128p, K=384 in 12 chunks of 32.
__global__ __launch_bounds__(256) void k_final(
    const unsigned short* __restrict__ Abf, const unsigned short* __restrict__ catT,
    const float* __restrict__ fb, float* __restrict__ out) {
  int pc = blockIdx.x, b = blockIdx.y;
  int t = threadIdx.x;
  __shared__ alignas(16) unsigned short fsm[20480];
  unsigned short* Ab0 = fsm;
  unsigned short* Ab1 = fsm + 5120;
  unsigned short* Bb0 = fsm + 10240;
  unsigned short* Bb1 = fsm + 15360;

  int w = t >> 6, l = t & 63;
  int wo = w >> 1, wp = w & 1;
  int lr = l & 15, lk = (l >> 4) * 8;

  f32x4 acc[4][4];
#pragma unroll
  for (int s = 0; s < 4; s++)
#pragma unroll
    for (int p = 0; p < 4; p++) acc[s][p] = 0.f;

  // stage chunk 0 direct
  for (int q = 0; q < 2; ++q) {
    int id = t + 256 * q;
    int o = id >> 2, seg = id & 3;
    uint4 va = *(const uint4*)(Abf + ((size_t)(b * 128 + o)) * 384 + seg * 8);
    *(uint4*)(&Ab0[o * 40 + seg * 8]) = va;
    uint4 vb = *(const uint4*)(catT + ((size_t)b * 4096 + pc * 128 + o) * 384 + seg * 8);
    *(uint4*)(&Bb0[o * 40 + seg * 8]) = vb;
  }
  __syncthreads();

  for (int c = 0; c < 12; ++c) {
    unsigned short* Acur = (c & 1) ? Ab1 : Ab0;
    unsigned short* Bcur = (c & 1) ? Bb1 : Bb0;
    unsigned short* Anxt = (c & 1) ? Ab0 : Ab1;
    unsigned short* Bnxt = (c & 1) ? Bb0 : Bb1;
    uint4 apf[2], bpf[2];
    if (c < 11) {
#pragma unroll
      for (int q = 0; q < 2; ++q) {
        int id = t + 256 * q;
        int o = id >> 2, seg = id & 3;
        apf[q] = *(const uint4*)(Abf + ((size_t)(b * 128 + o)) * 384 + (c + 1) * 32 + seg * 8);
        bpf[q] = *(const uint4*)(catT + ((size_t)b * 4096 + pc * 128 + o) * 384 + (c + 1) * 32 + seg * 8);
      }
    }
    {
      bf16x8 af[4], bf_[4];
#pragma unroll
      for (int sf = 0; sf < 4; ++sf)
        af[sf] = *(const bf16x8*)(&Acur[(wo * 64 + sf * 16 + lr) * 40 + lk]);
#pragma unroll
      for (int p = 0; p < 4; ++p)
        bf_[p] = *(const bf16x8*)(&Bcur[(wp * 64 + p * 16 + lr) * 40 + lk]);
#pragma unroll
      for (int sf = 0; sf < 4; ++sf)
#pragma unroll
        for (int p = 0; p < 4; ++p)
          acc[sf][p] = __builtin_amdgcn_mfma_f32_16x16x32_bf16(af[sf], bf_[p], acc[sf][p], 0, 0, 0);
    }
    if (c < 11) {
#pragma unroll
      for (int q = 0; q < 2; ++q) {
        int id = t + 256 * q;
        int o = id >> 2, seg = id & 3;
        *(uint4*)(&Anxt[o * 40 + seg * 8]) = apf[q];
        *(uint4*)(&Bnxt[o * 40 + seg * 8]) = bpf[q];
      }
    }
    __syncthreads();
  }

#pragma unroll
  for (int sf = 0; sf < 4; ++sf) {
    int obase = wo * 64 + sf * 16 + (l >> 4) * 4;
#pragma unroll
    for (int p = 0; p < 4; ++p) {
      int px = wp * 64 + p * 16 + lr;
#pragma unroll
      for (int q = 0; q < 4; ++q) {
        int o = obase + q;
        out[((size_t)(b * 128 + o)) * 4096 + pc * 128 + px] = acc[sf][p][q] + fb[o];
      }
    }
  }
}

extern "C" void kernel_launch(void* const* d_in, const int* in_sizes, int n_in,
                              void* d_out, int out_size, void* d_ws, size_t ws_size,
                              hipStream_t stream) {
  const float* F1 = (const float*)d_in[0];
  const float* F2 = (const float*)d_in[1];
  const float* F3 = (const float*)d_in[2];
  const float* conv_w = (const float*)d_in[3];
  const float* conv_b = (const float*)d_in[4];
  const float* qw = (const float*)d_in[5];
  const float* qb = (const float*)d_in[6];
  const float* kw = (const float*)d_in[7];
  const float* kb = (const float*)d_in[8];
  const float* vw = (const float*)d_in[9];
  const float* vb = (const float*)d_in[10];
  const float* ca1_w = (const float*)d_in[11];
  const float* ca1_b = (const float*)d_in[12];
  const float* ca2_w = (const float*)d_in[13];
  const float* ca2_b = (const float*)d_in[14];
  const float* c3d_w = (const float*)d_in[15];
  const float* c3d_b = (const float*)d_in[16];
  const float* out_w = (const float*)d_in[17];
  const float* out_b = (const float*)d_in[18];
  float* out = (float*)d_out;

  char* W = (char*)d_ws;
  unsigned short* INS  = (unsigned short*)W;                    // 25,165,824 B
  unsigned short* CATT = (unsigned short*)(W + 25165824);       // 25,165,824 B
  float* Qm    = (float*)(W + 50331648);                        // 3,145,728
  float* Km    = (float*)(W + 53477376);                        // 3,145,728
  float* Vm    = (float*)(W + 56623104);                        // 3,145,728
  float* OBm   = (float*)(W + 59768832);                        // 3,145,728
  float* XAVG  = (float*)(W + 62914560);                        // 3,145,728
  unsigned short* WG = (unsigned short*)(W + 66060288);         // 884,736
  float* QWT   = (float*)(W + 66945024);                        // 196,608
  float* KWT   = (float*)(W + 67141632);                        // 196,608
  float* VWT   = (float*)(W + 67338240);                        // 196,608
  float* COMB2 = (float*)(W + 67534848);                        // 196,608
  float* YPART = (float*)(W + 67731456);                        // 196,608
  float* Ym    = (float*)(W + 67928064);                        // 12,288
  float* YSE   = (float*)(W + 67940352);                        // 12,288
  float* FB    = (float*)(W + 67952640);                        // 512
  unsigned short* ABF = (unsigned short*)Qm;  // alias (Q dead after k_attn), 786,432 B

  k_wprep<<<1728, 256, 0, stream>>>(conv_w, WG);
  k_comb2<<<192, 256, 0, stream>>>(out_w, c3d_w, COMB2);
  k_fb<<<1, 128, 0, stream>>>(out_w, c3d_b, out_b, FB);
  k_qkvT<<<192, 256, 0, stream>>>(qw, kw, vw, QWT, KWT, VWT);
  k_prep<<<dim3(16, 8, 3), 256, 0, stream>>>(F1, F2, F3, INS, XAVG);
  k_proj<<<dim3(8, 8, 3), 256, 0, stream>>>(XAVG, QWT, qb, KWT, kb, VWT, vb, Qm, Km, Vm);
  k_attn<<<dim3(16, 8, 3), 256, 0, stream>>>(Qm, Km, Vm, OBm);
  k_conv<<<dim3(32, 8, 3), 256, 0, stream>>>(INS, WG, conv_b, OBm, CATT);
  k_semean1<<<dim3(16, 8), 384, 0, stream>>>(CATT, YPART);
  k_semean2<<<8, 384, 0, stream>>>(YPART, Ym);
  k_semlp<<<8, 384, 0, stream>>>(Ym, ca1_w, ca1_b, ca2_w, ca2_b, YSE);
  k_sefold<<<1536, 256, 0, stream>>>(COMB2, YSE, ABF);
  k_final<<<dim3(32, 8), 256, 0, stream>>>(ABF, CATT, FB, out);
}

// Round 3
// 275.047 us; speedup vs baseline: 4.8873x; 1.0978x over previous
//
#include <hip/hip_runtime.h>
#include <hip/hip_bf16.h>
#include <cstddef>

// B=8, C=128, H=W=64, S=4 (16x16=256 blocks), 3 branches.

typedef __bf16 bf16x8 __attribute__((ext_vector_type(8)));
typedef float f32x4 __attribute__((ext_vector_type(4)));

__device__ __forceinline__ unsigned short f2bf(float f) {
  unsigned int u = __float_as_uint(f);
  return (unsigned short)((u + 0x7fffu + ((u >> 16) & 1u)) >> 16);
}
__device__ __forceinline__ float bf2f(unsigned short h) {
  return __uint_as_float(((unsigned int)h) << 16);
}

// conv_w (3,co,ci,3,3) fp32 -> WG bf16 [i][tap][co][ci]; block per (i,co)
__global__ __launch_bounds__(256) void k_wprep(const float* __restrict__ conv_w,
                                               unsigned short* __restrict__ WG) {
  int blk = blockIdx.x;  // i*128+co
  int i = blk >> 7, co = blk & 127;
  int t = threadIdx.x;
  __shared__ float Lw[1152];
  const float* src = conv_w + (size_t)blk * 1152;
  for (int q = t; q < 1152; q += 256) Lw[q] = src[q];
  __syncthreads();
  for (int id = t; id < 576; id += 256) {
    int tap = id >> 6, cp = id & 63;
    unsigned int w = (unsigned int)f2bf(Lw[(cp * 2) * 9 + tap]) |
                     ((unsigned int)f2bf(Lw[(cp * 2 + 1) * 9 + tap]) << 16);
    *(unsigned int*)(WG + ((size_t)((i * 9 + tap) * 128 + co)) * 128 + cp * 2) = w;
  }
}

// comb2[o][j] = sum_m out_w[o,m]*c3d_w[m,c,d], j = d*128+c
__global__ void k_comb2(const float* __restrict__ out_w, const float* __restrict__ c3d_w,
                        float* __restrict__ comb2) {
  int idx = blockIdx.x * 256 + threadIdx.x;  // o*384 + j, 49152 total
  int j = idx % 384, o = idx / 384;
  int c = j & 127, d = j >> 7;
  float s = 0.f;
  for (int m = 0; m < 128; m++)
    s += out_w[o * 128 + m] * c3d_w[(m * 128 + c) * 3 + d];
  comb2[idx] = s;
}

__global__ void k_fb(const float* __restrict__ out_w, const float* __restrict__ c3d_b,
                     const float* __restrict__ out_b, float* __restrict__ fb) {
  int o = threadIdx.x;
  float s = out_b[o];
  for (int m = 0; m < 128; m++) s += out_w[o * 128 + m] * c3d_b[m];
  fb[o] = s;
}

// qw/kw/vw (3,C,C) -> transposed fp32 [i][k][c]
__global__ void k_qkvT(const float* __restrict__ qw, const float* __restrict__ kw,
                       const float* __restrict__ vw, float* __restrict__ qwT,
                       float* __restrict__ kwT, float* __restrict__ vwT) {
  int idx = blockIdx.x * 256 + threadIdx.x;
  if (idx >= 3 * 128 * 128) return;
  int c = idx & 127, k = (idx >> 7) & 127, i = idx >> 14;
  int src = (i * 128 + c) * 128 + k;
  qwT[idx] = qw[src];
  kwT[idx] = kw[src];
  vwT[idx] = vw[src];
}

// INS bf16 NHWC [i][b][y][x][ci]; block per (y,b,i)
__global__ __launch_bounds__(256) void k_prep(
    const float* __restrict__ F1, const float* __restrict__ F2, const float* __restrict__ F3,
    unsigned short* __restrict__ INS) {
  int y = blockIdx.x, b = blockIdx.y, i = blockIdx.z;
  int ib = i * 8 + b;
  int t = threadIdx.x;
  __shared__ unsigned short L[128 * 66];
  int x = t & 63, cg = t >> 6;
  if (i == 1) {
    const float* src = F2 + (((size_t)b * 128 + cg * 32) * 64 + y) * 64 + x;
#pragma unroll 4
    for (int k = 0; k < 32; ++k)
      L[(cg * 32 + k) * 66 + x] = f2bf(src[(size_t)k * 4096]);
  } else if (i == 2) {
    const float* src = F3 + (((size_t)b * 128 + cg * 32) * 128 + 2 * y) * 128 + 2 * x;
#pragma unroll 4
    for (int k = 0; k < 32; ++k) {
      const float* p = src + (size_t)k * 16384;
      float2 a = *(const float2*)p;
      float2 c = *(const float2*)(p + 128);
      L[(cg * 32 + k) * 66 + x] = f2bf(0.25f * (a.x + a.y + c.x + c.y));
    }
  } else {
    int ky = y >> 1, kx = x >> 1;
    int y0, y1, x0, x1;
    float wy0, wx0;
    if (y & 1) { y0 = ky; y1 = (ky + 1 < 32) ? ky + 1 : 31; wy0 = 0.75f; }
    else       { y0 = (ky - 1 > 0) ? ky - 1 : 0; y1 = ky;   wy0 = 0.25f; }
    if (x & 1) { x0 = kx; x1 = (kx + 1 < 32) ? kx + 1 : 31; wx0 = 0.75f; }
    else       { x0 = (kx - 1 > 0) ? kx - 1 : 0; x1 = kx;   wx0 = 0.25f; }
    const float* base = F1 + ((size_t)b * 128 + cg * 32) * 1024;
#pragma unroll 4
    for (int k = 0; k < 32; ++k) {
      const float* p = base + (size_t)k * 1024;
      float top = wx0 * p[y0 * 32 + x0] + (1.f - wx0) * p[y0 * 32 + x1];
      float bot = wx0 * p[y1 * 32 + x0] + (1.f - wx0) * p[y1 * 32 + x1];
      L[(cg * 32 + k) * 66 + x] = f2bf(wy0 * top + (1.f - wy0) * bot);
    }
  }
  __syncthreads();
  unsigned short* dst = INS + (((size_t)ib * 64 + y) * 64) * 128;
#pragma unroll
  for (int q = 0; q < 4; ++q) {
    int id = t + 256 * q;  // 1024 16B chunks
    int xx = id >> 4, cseg = id & 15;
    alignas(16) unsigned short tmp[8];
#pragma unroll
    for (int cc = 0; cc < 8; ++cc) tmp[cc] = L[(cseg * 8 + cc) * 66 + xx];
    *(uint4*)(dst + (size_t)xx * 128 + cseg * 8) = *(uint4*)tmp;
  }
}

// XAVG f32 [(i*8+b)*256+n][c] from INS; block per (yg,b,i), no LDS
__global__ __launch_bounds__(256) void k_xavg2(const unsigned short* __restrict__ INS,
                                               float* __restrict__ XAVG) {
  int yg = blockIdx.x, b = blockIdx.y, i = blockIdx.z;
  int ib = i * 8 + b;
  int t = threadIdx.x;
  int cp = t & 63, q = t >> 6;
  float accL[4], accH[4];
#pragma unroll
  for (int z = 0; z < 4; z++) { accL[z] = 0.f; accH[z] = 0.f; }
#pragma unroll
  for (int ry = 0; ry < 4; ++ry) {
    int y = yg * 4 + ry;
    const unsigned short* row = INS + (((size_t)ib * 64 + y) * 64) * 128;
#pragma unroll
    for (int e = 0; e < 16; ++e) {
      int xx = q * 16 + e;
      unsigned int v = *(const unsigned int*)(row + (size_t)xx * 128 + cp * 2);
      accL[e >> 2] += bf2f((unsigned short)(v & 0xffffu));
      accH[e >> 2] += bf2f((unsigned short)(v >> 16));
    }
  }
#pragma unroll
  for (int nn = 0; nn < 4; ++nn) {
    int n = yg * 16 + q * 4 + nn;
    float2 w = make_float2(accL[nn] * (1.f / 16.f), accH[nn] * (1.f / 16.f));
    *(float2*)(XAVG + ((size_t)(ib * 256 + n)) * 128 + cp * 2) = w;
  }
}

// Q,K,Vb projections. block=(nc,b,i): 32 n rows each.
__global__ __launch_bounds__(256) void k_proj(
    const float* __restrict__ xavg, const float* __restrict__ qwT, const float* __restrict__ qb,
    const float* __restrict__ kwT, const float* __restrict__ kb,
    const float* __restrict__ vwT, const float* __restrict__ vb,
    float* __restrict__ Q, float* __restrict__ Km, float* __restrict__ Vb) {
  int nc = blockIdx.x, b = blockIdx.y, i = blockIdx.z;
  int ib = i * 8 + b;
  int t = threadIdx.x;
  __shared__ float xs[32 * 128];
  for (int q = 0; q < 4; ++q) {
    int id = t + 256 * q;
    int n = id >> 5, seg = id & 31;
    float4 v = *(const float4*)(xavg + ((size_t)(ib * 256 + nc * 32 + n)) * 128 + seg * 4);
    *(float4*)(xs + n * 128 + seg * 4) = v;
  }
  __syncthreads();
  int c = t & 127, nh = t >> 7;
  float aq[16], ak[16], av[16];
#pragma unroll
  for (int z = 0; z < 16; z++) { aq[z] = 0.f; ak[z] = 0.f; av[z] = 0.f; }
  for (int k = 0; k < 128; ++k) {
    float wq = qwT[(i * 128 + k) * 128 + c];
    float wk = kwT[(i * 128 + k) * 128 + c];
    float wv = vwT[(i * 128 + k) * 128 + c];
#pragma unroll
    for (int nn = 0; nn < 16; ++nn) {
      float xv = xs[(nh * 16 + nn) * 128 + k];
      aq[nn] += xv * wq; ak[nn] += xv * wk; av[nn] += xv * wv;
    }
  }
  float bq = qb[i * 128 + c], bk = kb[i * 128 + c], bv = vb[i * 128 + c];
#pragma unroll
  for (int nn = 0; nn < 16; ++nn) {
    size_t row = ((size_t)(ib * 256 + nc * 32 + nh * 16 + nn)) * 128 + c;
    Q[row] = aq[nn] + bq;
    Km[row] = ak[nn] + bk;
    Vb[row] = 16.f * (av[nn] + bv);
  }
}

// attention: block=(nc,b,i): 16 q-rows; 2-pass softmax, K/V chunks in LDS
__global__ __launch_bounds__(256) void k_attn(
    const float* __restrict__ Q, const float* __restrict__ K, const float* __restrict__ V,
    float* __restrict__ OB) {
  int nc = blockIdx.x, b = blockIdx.y, i = blockIdx.z;
  int ib = i * 8 + b;
  int t = threadIdx.x;
  __shared__ float Qs[16 * 132];
  __shared__ float Ss[16 * 257];
  __shared__ float KVs[32 * 132];
  for (int q = 0; q < 2; ++q) {
    int id = t + 256 * q;
    int n = id >> 5, seg = id & 31;
    float4 v = *(const float4*)(Q + ((size_t)(ib * 256 + nc * 16 + n)) * 128 + seg * 4);
    *(float4*)(Qs + n * 132 + seg * 4) = v;
  }
  int n = t >> 4, ms = t & 15;
  const float SC = 0.08838834764831845f;
  for (int mc = 0; mc < 8; ++mc) {
    __syncthreads();
    for (int q = 0; q < 4; ++q) {
      int id = t + 256 * q;
      int m = id >> 5, seg = id & 31;
      float4 v = *(const float4*)(K + ((size_t)(ib * 256 + mc * 32 + m)) * 128 + seg * 4);
      *(float4*)(KVs + m * 132 + seg * 4) = v;
    }
    __syncthreads();
    float s0 = 0.f, s1 = 0.f;
    const float* qrow = Qs + n * 132;
    const float* k0p = KVs + (ms * 2) * 132;
    for (int kg = 0; kg < 32; ++kg) {
      float4 qv = *(const float4*)(qrow + kg * 4);
      float4 k0 = *(const float4*)(k0p + kg * 4);
      float4 k1 = *(const float4*)(k0p + 132 + kg * 4);
      s0 += qv.x * k0.x + qv.y * k0.y + qv.z * k0.z + qv.w * k0.w;
      s1 += qv.x * k1.x + qv.y * k1.y + qv.z * k1.z + qv.w * k1.w;
    }
    Ss[n * 257 + mc * 32 + ms * 2 + 0] = s0 * SC;
    Ss[n * 257 + mc * 32 + ms * 2 + 1] = s1 * SC;
  }
  __syncthreads();
  {
    float vals[16];
    float mx = -1e30f;
#pragma unroll
    for (int j = 0; j < 16; ++j) { vals[j] = Ss[n * 257 + ms + 16 * j]; mx = fmaxf(mx, vals[j]); }
    for (int d = 1; d < 16; d <<= 1) mx = fmaxf(mx, __shfl_xor(mx, d));
    float sum = 0.f;
#pragma unroll
    for (int j = 0; j < 16; ++j) { vals[j] = __expf(vals[j] - mx); sum += vals[j]; }
    for (int d = 1; d < 16; d <<= 1) sum += __shfl_xor(sum, d);
    float inv = 1.f / sum;
#pragma unroll
    for (int j = 0; j < 16; ++j) Ss[n * 257 + ms + 16 * j] = vals[j] * inv;
  }
  int cs = ms;
  float acc[8];
#pragma unroll
  for (int z = 0; z < 8; z++) acc[z] = 0.f;
  for (int mc = 0; mc < 8; ++mc) {
    __syncthreads();
    for (int q = 0; q < 4; ++q) {
      int id = t + 256 * q;
      int m = id >> 5, seg = id & 31;
      float4 v = *(const float4*)(V + ((size_t)(ib * 256 + mc * 32 + m)) * 128 + seg * 4);
      *(float4*)(KVs + m * 132 + seg * 4) = v;
    }
    __syncthreads();
    for (int m = 0; m < 32; ++m) {
      float p = Ss[n * 257 + mc * 32 + m];
      const float* vrow = KVs + m * 132 + cs * 8;
      float4 v0 = *(const float4*)(vrow);
      float4 v1 = *(const float4*)(vrow + 4);
      acc[0] += p * v0.x; acc[1] += p * v0.y; acc[2] += p * v0.z; acc[3] += p * v0.w;
      acc[4] += p * v1.x; acc[5] += p * v1.y; acc[6] += p * v1.z; acc[7] += p * v1.w;
    }
  }
  float* orow = OB + ((size_t)(ib * 256 + nc * 16 + n)) * 128 + cs * 8;
  *(float4*)(orow) = make_float4(acc[0], acc[1], acc[2], acc[3]);
  *(float4*)(orow + 4) = make_float4(acc[4], acc[5], acc[6], acc[7]);
}

// conv3x3 via bf16 MFMA implicit GEMM + attention add -> catT bf16 [b][p][j]
__global__ __launch_bounds__(256) void k_conv(
    const unsigned short* __restrict__ INS, const unsigned short* __restrict__ WG,
    const float* __restrict__ conv_b, const float* __restrict__ OB,
    unsigned short* __restrict__ catT) {
  int y0 = blockIdx.x * 2, b = blockIdx.y, i = blockIdx.z;
  int ib = i * 8 + b;
  int t = threadIdx.x;
  __shared__ alignas(16) unsigned short smem[20800];
  unsigned short* Xs = smem;
  unsigned short* Wb0 = smem + 10560;
  unsigned short* Wb1 = smem + 15680;

  int w = t >> 6, l = t & 63;
  int wm = w >> 1, wr = w & 1;
  int lr = l & 15, lk = (l >> 4) * 8;

  f32x4 acc[4][4];
#pragma unroll
  for (int s = 0; s < 4; s++)
#pragma unroll
    for (int p = 0; p < 4; p++) acc[s][p] = 0.f;

  auto stageX = [&](int cc) {
    for (int cI = t; cI < 1056; cI += 256) {
      int seg = cI & 3, rj = cI >> 2;
      int r = rj / 66, j = rj - r * 66;
      int yy = y0 - 1 + r, xx = j - 1;
      uint4 v = {0u, 0u, 0u, 0u};
      if (yy >= 0 && yy < 64 && xx >= 0 && xx < 64)
        v = *(const uint4*)(INS + (((size_t)ib * 64 + yy) * 64 + xx) * 128 + cc * 32 + seg * 8);
      *(uint4*)(&Xs[(r * 66 + j) * 40 + seg * 8]) = v;
    }
  };

  stageX(0);
  {
    for (int q = 0; q < 2; ++q) {
      int id = t + 256 * q;
      int co = id >> 2, seg = id & 3;
      uint4 v = *(const uint4*)(WG + ((size_t)(i * 9 + 0) * 128 + co) * 128 + 0 * 32 + seg * 8);
      *(uint4*)(&Wb0[co * 40 + seg * 8]) = v;
    }
  }
  __syncthreads();

  for (int s = 0; s < 36; ++s) {
    int tap = s % 9, cc = s / 9;
    int dy = tap / 3, dx = tap - dy * 3;
    unsigned short* Wcur = (s & 1) ? Wb1 : Wb0;
    unsigned short* Wnxt = (s & 1) ? Wb0 : Wb1;
    uint4 wpf[2];
    if (s < 35) {
      int sN = s + 1, tapN = sN % 9, ccN = sN / 9;
#pragma unroll
      for (int q = 0; q < 2; ++q) {
        int id = t + 256 * q;
        int co = id >> 2, seg = id & 3;
        wpf[q] = *(const uint4*)(WG + ((size_t)(i * 9 + tapN) * 128 + co) * 128 + ccN * 32 + seg * 8);
      }
    }
    {
      bf16x8 af[4], bf_[4];
#pragma unroll
      for (int sf = 0; sf < 4; ++sf)
        af[sf] = *(const bf16x8*)(&Wcur[(wm * 64 + sf * 16 + lr) * 40 + lk]);
      int r = wr + dy;
#pragma unroll
      for (int p = 0; p < 4; ++p) {
        int j = p * 16 + lr + dx;
        bf_[p] = *(const bf16x8*)(&Xs[(r * 66 + j) * 40 + lk]);
      }
#pragma unroll
      for (int sf = 0; sf < 4; ++sf)
#pragma unroll
        for (int p = 0; p < 4; ++p)
          acc[sf][p] = __builtin_amdgcn_mfma_f32_16x16x32_bf16(af[sf], bf_[p], acc[sf][p], 0, 0, 0);
    }
    if (tap == 8 && s < 35) {
      __syncthreads();
      stageX(cc + 1);
    }
    if (s < 35) {
#pragma unroll
      for (int q = 0; q < 2; ++q) {
        int id = t + 256 * q;
        int co = id >> 2, seg = id & 3;
        *(uint4*)(&Wnxt[co * 40 + seg * 8]) = wpf[q];
      }
    }
    __syncthreads();
  }

  unsigned short* Tt = smem;  // [128 ploc][136 co]
  float cb[4][4];
#pragma unroll
  for (int sf = 0; sf < 4; ++sf)
#pragma unroll
    for (int q = 0; q < 4; ++q)
      cb[sf][q] = conv_b[i * 128 + wm * 64 + sf * 16 + (l >> 4) * 4 + q];
#pragma unroll
  for (int sf = 0; sf < 4; ++sf) {
#pragma unroll
    for (int p = 0; p < 4; ++p) {
      int px = p * 16 + lr;
      int n = ((y0 + wr) >> 2) * 16 + (px >> 2);
      const float* ob = OB + ((size_t)(ib * 256 + n)) * 128;
      int cobase = wm * 64 + sf * 16 + (l >> 4) * 4;
      float v0 = acc[sf][p][0] + cb[sf][0] + ob[cobase + 0];
      float v1 = acc[sf][p][1] + cb[sf][1] + ob[cobase + 1];
      float v2 = acc[sf][p][2] + cb[sf][2] + ob[cobase + 2];
      float v3 = acc[sf][p][3] + cb[sf][3] + ob[cobase + 3];
      int ploc = wr * 64 + px;
      unsigned int pk0 = (unsigned int)f2bf(v0) | ((unsigned int)f2bf(v1) << 16);
      unsigned int pk1 = (unsigned int)f2bf(v2) | ((unsigned int)f2bf(v3) << 16);
      *(unsigned int*)(&Tt[ploc * 136 + cobase]) = pk0;
      *(unsigned int*)(&Tt[ploc * 136 + cobase + 2]) = pk1;
    }
  }
  __syncthreads();
  for (int c2 = t; c2 < 2048; c2 += 256) {
    int ploc = c2 >> 4, seg = c2 & 15;
    uint4 v = *(const uint4*)(&Tt[ploc * 136 + seg * 8]);
    int yy = y0 + (ploc >> 6), xx = ploc & 63;
    *(uint4*)(catT + (((size_t)b * 4096) + yy * 64 + xx) * 384 + i * 128 + seg * 8) = v;
  }
}

// SE mean stage 1: partial sums over 256 rows of p
__global__ void k_semean1(const unsigned short* __restrict__ catT, float* __restrict__ Ypart) {
  int pc = blockIdx.x, b = blockIdx.y;
  int j = threadIdx.x;  // 384
  const unsigned short* base = catT + ((size_t)b * 4096 + pc * 256) * 384 + j;
  float s = 0.f;
#pragma unroll 4
  for (int r = 0; r < 256; ++r) s += bf2f(base[(size_t)r * 384]);
  Ypart[(b * 16 + pc) * 384 + j] = s;
}

__global__ void k_semean2(const float* __restrict__ Ypart, float* __restrict__ Y) {
  int b = blockIdx.x;
  int j = threadIdx.x;
  float s = 0.f;
#pragma unroll
  for (int pc = 0; pc < 16; ++pc) s += Ypart[(b * 16 + pc) * 384 + j];
  Y[b * 384 + j] = s * (1.f / 4096.f);
}

__global__ void k_semlp(const float* __restrict__ y,
                        const float* __restrict__ ca1_w, const float* __restrict__ ca1_b,
                        const float* __restrict__ ca2_w, const float* __restrict__ ca2_b,
                        float* __restrict__ yse) {
  int b = blockIdx.x;
  int t = threadIdx.x;  // 384
  __shared__ float ysh[384];
  __shared__ float z1[24];
  ysh[t] = y[b * 384 + t];
  __syncthreads();
  if (t < 24) {
    float s = ca1_b[t];
    for (int k = 0; k < 384; k++) s += ca1_w[t * 384 + k] * ysh[k];
    z1[t] = fmaxf(s, 0.f);
  }
  __syncthreads();
  float s = ca2_b[t];
  for (int k = 0; k < 24; k++) s += ca2_w[t * 24 + k] * z1[k];
  yse[b * 384 + t] = 1.f / (1.f + expf(-s));
}

// A_bf[b][o][j] = bf16(comb2[o][j] * yse[b][j])
__global__ void k_sefold(const float* __restrict__ comb2, const float* __restrict__ yse,
                         unsigned short* __restrict__ Abf) {
  int idx = blockIdx.x * 256 + threadIdx.x;
  int j = idx % 384;
  int bo = idx / 384;
  int o = bo & 127, b = bo >> 7;
  Abf[idx] = f2bf(comb2[o * 384 + j] * yse[b * 384 + j]);
}

// final GEMM: out[b,o,p] = sum_j Abf[b,o,j] * catT[b,p,j] + fb[o]
__global__ __launch_bounds__(256) void k_final(
    const unsigned short* __restrict__ Abf, const unsigned short* __restrict__ catT,
    const float* __restrict__ fb, float* __restrict__ out) {
  int pc = blockIdx.x, b = blockIdx.y;
  int t = threadIdx.x;
  __shared__ alignas(16) unsigned short fsm[20480];
  unsigned short* Ab0 = fsm;
  unsigned short* Ab1 = fsm + 5120;
  unsigned short* Bb0 = fsm + 10240;
  unsigned short* Bb1 = fsm + 15360;

  int w = t >> 6, l = t & 63;
  int wo = w >> 1, wp = w & 1;
  int lr = l & 15, lk = (l >> 4) * 8;

  f32x4 acc[4][4];
#pragma unroll
  for (int s = 0; s < 4; s++)
#pragma unroll
    for (int p = 0; p < 4; p++) acc[s][p] = 0.f;

  for (int q = 0; q < 2; ++q) {
    int id = t + 256 * q;
    int o = id >> 2, seg = id & 3;
    uint4 va = *(const uint4*)(Abf + ((size_t)(b * 128 + o)) * 384 + seg * 8);
    *(uint4*)(&Ab0[o * 40 + seg * 8]) = va;
    uint4 vb = *(const uint4*)(catT + ((size_t)b * 4096 + pc * 128 + o) * 384 + seg * 8);
    *(uint4*)(&Bb0[o * 40 + seg * 8]) = vb;
  }
  __syncthreads();

  for (int c = 0; c < 12; ++c) {
    unsigned short* Acur = (c & 1) ? Ab1 : Ab0;
    unsigned short* Bcur = (c & 1) ? Bb1 : Bb0;
    unsigned short* Anxt = (c & 1) ? Ab0 : Ab1;
    unsigned short* Bnxt = (c & 1) ? Bb0 : Bb1;
    uint4 apf[2], bpf[2];
    if (c < 11) {
#pragma unroll
      for (int q = 0; q < 2; ++q) {
        int id = t + 256 * q;
        int o = id >> 2, seg = id & 3;
        apf[q] = *(const uint4*)(Abf + ((size_t)(b * 128 + o)) * 384 + (c + 1) * 32 + seg * 8);
        bpf[q] = *(const uint4*)(catT + ((size_t)b * 4096 + pc * 128 + o) * 384 + (c + 1) * 32 + seg * 8);
      }
    }
    {
      bf16x8 af[4], bf_[4];
#pragma unroll
      for (int sf = 0; sf < 4; ++sf)
        af[sf] = *(const bf16x8*)(&Acur[(wo * 64 + sf * 16 + lr) * 40 + lk]);
#pragma unroll
      for (int p = 0; p < 4; ++p)
        bf_[p] = *(const bf16x8*)(&Bcur[(wp * 64 + p * 16 + lr) * 40 + lk]);
#pragma unroll
      for (int sf = 0; sf < 4; ++sf)
#pragma unroll
        for (int p = 0; p < 4; ++p)
          acc[sf][p] = __builtin_amdgcn_mfma_f32_16x16x32_bf16(af[sf], bf_[p], acc[sf][p], 0, 0, 0);
    }
    if (c < 11) {
#pragma unroll
      for (int q = 0; q < 2; ++q) {
        int id = t + 256 * q;
        int o = id >> 2, seg = id & 3;
        *(uint4*)(&Anxt[o * 40 + seg * 8]) = apf[q];
        *(uint4*)(&Bnxt[o * 40 + seg * 8]) = bpf[q];
      }
    }
    __syncthreads();
  }

#pragma unroll
  for (int sf = 0; sf < 4; ++sf) {
    int obase = wo * 64 + sf * 16 + (l >> 4) * 4;
#pragma unroll
    for (int p = 0; p < 4; ++p) {
      int px = wp * 64 + p * 16 + lr;
#pragma unroll
      for (int q = 0; q < 4; ++q) {
        int o = obase + q;
        out[((size_t)(b * 128 + o)) * 4096 + pc * 128 + px] = acc[sf][p][q] + fb[o];
      }
    }
  }
}

extern "C" void kernel_launch(void* const* d_in, const int* in_sizes, int n_in,
                              void* d_out, int out_size, void* d_ws, size_t ws_size,
                              hipStream_t stream) {
  const float* F1 = (const float*)d_in[0];
  const float* F2 = (const float*)d_in[1];
  const float* F3 = (const float*)d_in[2];
  const float* conv_w = (const float*)d_in[3];
  const float* conv_b = (const float*)d_in[4];
  const float* qw = (const float*)d_in[5];
  const float* qb = (const float*)d_in[6];
  const float* kw = (const float*)d_in[7];
  const float* kb = (const float*)d_in[8];
  const float* vw = (const float*)d_in[9];
  const float* vb = (const float*)d_in[10];
  const float* ca1_w = (const float*)d_in[11];
  const float* ca1_b = (const float*)d_in[12];
  const float* ca2_w = (const float*)d_in[13];
  const float* ca2_b = (const float*)d_in[14];
  const float* c3d_w = (const float*)d_in[15];
  const float* c3d_b = (const float*)d_in[16];
  const float* out_w = (const float*)d_in[17];
  const float* out_b = (const float*)d_in[18];
  float* out = (float*)d_out;

  char* W = (char*)d_ws;
  unsigned short* INS  = (unsigned short*)W;                    // 25,165,824 B
  unsigned short* CATT = (unsigned short*)(W + 25165824);       // 25,165,824 B
  float* Qm    = (float*)(W + 50331648);                        // 3,145,728
  float* Km    = (float*)(W + 53477376);                        // 3,145,728
  float* Vm    = (float*)(W + 56623104);                        // 3,145,728
  float* OBm   = (float*)(W + 59768832);                        // 3,145,728
  float* XAVG  = (float*)(W + 62914560);                        // 3,145,728
  unsigned short* WG = (unsigned short*)(W + 66060288);         // 884,736
  float* QWT   = (float*)(W + 66945024);                        // 196,608
  float* KWT   = (float*)(W + 67141632);                        // 196,608
  float* VWT   = (float*)(W + 67338240);                        // 196,608
  float* COMB2 = (float*)(W + 67534848);                        // 196,608
  float* YPART = (float*)(W + 67731456);                        // 196,608
  float* Ym    = (float*)(W + 67928064);                        // 12,288
  float* YSE   = (float*)(W + 67940352);                        // 12,288
  float* FB    = (float*)(W + 67952640);                        // 512
  unsigned short* ABF = (unsigned short*)Qm;  // alias (Q dead after k_attn)

  k_wprep<<<384, 256, 0, stream>>>(conv_w, WG);
  k_comb2<<<192, 256, 0, stream>>>(out_w, c3d_w, COMB2);
  k_fb<<<1, 128, 0, stream>>>(out_w, c3d_b, out_b, FB);
  k_qkvT<<<192, 256, 0, stream>>>(qw, kw, vw, QWT, KWT, VWT);
  k_prep<<<dim3(64, 8, 3), 256, 0, stream>>>(F1, F2, F3, INS);
  k_xavg2<<<dim3(16, 8, 3), 256, 0, stream>>>(INS, XAVG);
  k_proj<<<dim3(8, 8, 3), 256, 0, stream>>>(XAVG, QWT, qb, KWT, kb, VWT, vb, Qm, Km, Vm);
  k_attn<<<dim3(16, 8, 3), 256, 0, stream>>>(Qm, Km, Vm, OBm);
  k_conv<<<dim3(32, 8, 3), 256, 0, stream>>>(INS, WG, conv_b, OBm, CATT);
  k_semean1<<<dim3(16, 8), 384, 0, stream>>>(CATT, YPART);
  k_semean2<<<8, 384, 0, stream>>>(YPART, Ym);
  k_semlp<<<8, 384, 0, stream>>>(Ym, ca1_w, ca1_b, ca2_w, ca2_b, YSE);
  k_sefold<<<1536, 256, 0, stream>>>(COMB2, YSE, ABF);
  k_final<<<dim3(32, 8), 256, 0, stream>>>(ABF, CATT, FB, out);
}